// Round 8
// baseline (521.146 us; speedup 1.0000x reference)
//
#include <hip/hip_runtime.h>
#include <hip/hip_bf16.h>

// FeatureAttention on MI355X — Round 8: faithful 8-phase counted-vmcnt GEMM
// (m201 template): BK=64 as 2 k-halves, 4 phases/K-tile, per-phase
// {ds_read | stage-half | barrier | lgkm(0)+sched_barrier | setprio MFMA},
// ONE vmcnt(4) gate per K-tile (drain only at epilogue tiles).
// Ledger: tile T stages a1(T+1),b1(T+1),a0(T+2),b0(T+2) (1 half/phase).
// Pipeline: wconvT(x5) -> LN1 -> fused QKV GEMM -> attn(+LN2) -> FFN1 -> FFN2.

#define D_DIM 512
#define NROWS 32768
#define NBE   512

typedef __attribute__((ext_vector_type(8))) short bf16x8;
typedef __attribute__((ext_vector_type(4))) float f32x4;

typedef const __attribute__((address_space(1))) unsigned g_u32;
typedef __attribute__((address_space(3))) unsigned lds_u32;

__device__ __forceinline__ short f2bf(float f) {
  union { float f; unsigned u; } c; c.f = f;
  unsigned u = c.u;
  unsigned r = (u + 0x7FFFu + ((u >> 16) & 1u)) >> 16;   // RNE
  return (short)r;
}
__device__ __forceinline__ float bf2f(short s) {
  union { unsigned u; float f; } c; c.u = ((unsigned)(unsigned short)s) << 16;
  return c.f;
}

// ---- LDS-tiled transpose + fp32->bf16: Wt[n][k] = bf16(W[k][n]) ----
__global__ __launch_bounds__(256) void wconvT(const float* __restrict__ W,
                                              short* __restrict__ Wt,
                                              int K, int N) {
  __shared__ float tile[32][33];
  const int t = threadIdx.x;
  const int r  = t >> 3;            // 0..31
  const int c4 = (t & 7) * 4;       // 0,4,...,28
  const long k0 = (long)blockIdx.y * 32;
  const long n0 = (long)blockIdx.x * 32;
  float4 v = *(const float4*)&W[(k0 + r) * N + n0 + c4];
  tile[r][c4 + 0] = v.x; tile[r][c4 + 1] = v.y;
  tile[r][c4 + 2] = v.z; tile[r][c4 + 3] = v.w;
  __syncthreads();
  union { short sh[4]; int2 v; } o;
#pragma unroll
  for (int j = 0; j < 4; ++j) o.sh[j] = f2bf(tile[c4 + j][r]);
  *(int2*)&Wt[(n0 + r) * K + k0 + c4] = o.v;
}

// ---- LayerNorm over D=512, fp32 in -> bf16 out. One wave per row. ----
__global__ __launch_bounds__(256) void ln_kernel(const float* __restrict__ x,
                                                 const float* __restrict__ gam,
                                                 const float* __restrict__ bet,
                                                 short* __restrict__ h) {
  const int t = threadIdx.x;
  const long row = (long)blockIdx.x * 4 + (t >> 6);
  const int lane = t & 63;
  const float* xr = x + row * D_DIM + lane * 8;
  float4 a = *(const float4*)xr;
  float4 b = *(const float4*)(xr + 4);
  float xs[8] = {a.x, a.y, a.z, a.w, b.x, b.y, b.z, b.w};
  float s = 0.f, ss = 0.f;
#pragma unroll
  for (int j = 0; j < 8; ++j) { s += xs[j]; ss += xs[j] * xs[j]; }
#pragma unroll
  for (int m = 1; m < 64; m <<= 1) {
    s  += __shfl_xor(s, m);
    ss += __shfl_xor(ss, m);
  }
  float mean = s * (1.f / D_DIM);
  float var  = ss * (1.f / D_DIM) - mean * mean;
  float rstd = rsqrtf(var + 1e-5f);
  union { short sh[8]; int4 v; } o;
#pragma unroll
  for (int j = 0; j < 8; ++j) {
    int d = lane * 8 + j;
    o.sh[j] = f2bf((xs[j] - mean) * rstd * gam[d] + bet[d]);
  }
  *(int4*)&h[row * D_DIM + lane * 8] = o.v;
}

// ---- 256x256 BK=64 8-phase counted-vmcnt bf16 MFMA GEMM ----
// out[M,N] = A[M,K] @ Bt[N,K]^T + bias (+resid). 512 threads = 8 waves (2x4),
// wave owns 128x64 = 8x4 frags. K-tile = 64 = 2 k-halves of 32.
// LDS: A[2buf][2kh][16KB] + B same = 128KB. Half = 256 rows x 32k, stored
// fragment-order: chunk c (16 rows) at c*1KB, lane l -> (row=c*16+(l&15),
// k=kh*32+(l>>4)*8) -> all ds_read_b128 are 1KB-linear, conflict-free
// (R4-R7: measured 0). Stage: 2 block-wide gload_lds per half (instr i=0,1
// covers rows i*128+wave*16+(l&15)); LDS dest = uniform + lane*16 (m104 ok).
// Phases per tile T (buf bb=T&1, nb=bb^1):
//  ph1: read af0-3,bf0-3 @kh0 (8 ds); stage a1(T+1)->A[nb][1]
//  ph2: read af4-7 @kh0 (4 ds, reuse bf); stage b1(T+1)->B[nb][1]
//  ph3: read af0-3,bf0-3 @kh1 (8 ds);    stage a0(T+2)->A[bb][0]
//  ph4: read af4-7 @kh1 (4 ds);          stage b0(T+2)->B[bb][0]
//  each phase: ... ; s_barrier; lgkmcnt(0); sched_barrier(0); setprio(1);
//              16 MFMA; setprio(0); s_barrier  (ph4's 2nd barrier = gate's)
//  gate (once/tile): vmcnt(4) if T+2<nt else vmcnt(0); s_barrier.
// WAR safety: each staged slot's last reader finished >=1 barrier earlier
// (a1(T-1) read ph3-4 of T-1; a0(T) read ph1-2 of T; etc. — all checked).
template <int OUT_BF16, int RESID>
__global__ __launch_bounds__(512) void gemm256(
    const short* __restrict__ A, const short* __restrict__ Bt,
    const float* __restrict__ bias0, const float* __restrict__ bias1,
    const float* __restrict__ bias2,
    void* __restrict__ out0, void* __restrict__ out1, void* __restrict__ out2,
    const float* __restrict__ resid, int K, int nsplit) {
  extern __shared__ short smem[];   // A: [(bb*2+kh)*8192]; B: +32768
  const int t = threadIdx.x;
  const int wave = t >> 6, lane = t & 63;
  const int lr = lane & 15, g = lane >> 4;
  const int wr = wave >> 2, wc = wave & 3;   // 2 x 4 wave grid

  // XCD-chunked bijective swizzle (T1); nwg % 8 == 0 for all our grids.
  const int gx = gridDim.x;
  const int nwg = gx * gridDim.y;
  const int hid = blockIdx.y * gx + blockIdx.x;
  const int lid = (hid & 7) * (nwg >> 3) + (hid >> 3);
  const int m0 = (lid / gx) * 256;
  const int n0 = (lid % gx) * 256;

  const int seg = n0 / nsplit;               // block-uniform
  const int ncol0 = n0 - seg * nsplit;
  const float* bias = seg == 0 ? bias0 : (seg == 1 ? bias1 : bias2);
  void* outp = seg == 0 ? out0 : (seg == 1 ? out1 : out2);

  // staging: thread -> global row m0|n0 + i*128 + wave*16 + (l&15),
  // k = T*64 + kh*32 + (l>>4)*8.
  const short* gA0 = &A[(long)(m0 + wave * 16 + lr) * K + g * 8];
  const short* gB0 = &Bt[(long)(n0 + wave * 16 + lr) * K + g * 8];
  const long rstep = 128L * K;
  const int ldst = wave * 512 + lane * 8;    // shorts within a half

#define STG_A(bb, kh, Ti)                                                      \
  do {                                                                         \
    const long gk = (long)(Ti) * 64 + (kh) * 32;                               \
    __builtin_amdgcn_global_load_lds((g_u32*)(gA0 + gk),                       \
        (lds_u32*)(smem + ((bb) * 2 + (kh)) * 8192 + ldst), 16, 0, 0);         \
    __builtin_amdgcn_global_load_lds((g_u32*)(gA0 + rstep + gk),               \
        (lds_u32*)(smem + ((bb) * 2 + (kh)) * 8192 + 4096 + ldst), 16, 0, 0);  \
  } while (0)
#define STG_B(bb, kh, Ti)                                                      \
  do {                                                                         \
    const long gk = (long)(Ti) * 64 + (kh) * 32;                               \
    __builtin_amdgcn_global_load_lds((g_u32*)(gB0 + gk),                       \
        (lds_u32*)(smem + 32768 + ((bb) * 2 + (kh)) * 8192 + ldst), 16, 0, 0); \
    __builtin_amdgcn_global_load_lds((g_u32*)(gB0 + rstep + gk),               \
        (lds_u32*)(smem + 32768 + ((bb) * 2 + (kh)) * 8192 + 4096 + ldst),     \
        16, 0, 0);                                                             \
  } while (0)

  f32x4 acc[8][4];
  const f32x4 vzero = {0.f, 0.f, 0.f, 0.f};
#pragma unroll
  for (int mi = 0; mi < 8; ++mi)
#pragma unroll
    for (int ni = 0; ni < 4; ++ni) acc[mi][ni] = vzero;

  const int nt = K >> 6;
  // prologue FIFO: a0(0),b0(0),a1(0),b1(0),a0(1),b0(1); keep last 2 in flight
  STG_A(0, 0, 0); STG_B(0, 0, 0);
  STG_A(0, 1, 0); STG_B(0, 1, 0);
  STG_A(1, 0, 1); STG_B(1, 0, 1);
  asm volatile("s_waitcnt vmcnt(4)" ::: "memory");
  __builtin_amdgcn_s_barrier();

  const int fo = lane * 8;
  for (int T = 0; T < nt; ++T) {
    const int bb = T & 1, nb = bb ^ 1;
    const short* sA0 = smem + (bb * 2 + 0) * 8192;          // A kh0
    const short* sA1 = smem + (bb * 2 + 1) * 8192;          // A kh1
    const short* sB0 = smem + 32768 + (bb * 2 + 0) * 8192;  // B kh0
    const short* sB1 = smem + 32768 + (bb * 2 + 1) * 8192;  // B kh1
    bf16x8 af[4], bfr[4];

    // ---- ph1: kh0, m-half0 ----
#pragma unroll
    for (int i = 0; i < 4; ++i) af[i]  = *(const bf16x8*)&sA0[(wr * 8 + i) * 512 + fo];
#pragma unroll
    for (int i = 0; i < 4; ++i) bfr[i] = *(const bf16x8*)&sB0[(wc * 4 + i) * 512 + fo];
    if (T + 1 < nt) STG_A(nb, 1, T + 1);
    __builtin_amdgcn_s_barrier();
    asm volatile("s_waitcnt lgkmcnt(0)" ::: "memory");
    __builtin_amdgcn_sched_barrier(0);
    __builtin_amdgcn_s_setprio(1);
#pragma unroll
    for (int mi = 0; mi < 4; ++mi)
#pragma unroll
      for (int ni = 0; ni < 4; ++ni)
        acc[mi][ni] = __builtin_amdgcn_mfma_f32_16x16x32_bf16(af[mi], bfr[ni], acc[mi][ni], 0, 0, 0);
    __builtin_amdgcn_s_setprio(0);
    __builtin_amdgcn_s_barrier();

    // ---- ph2: kh0, m-half1 (reuse bfr) ----
#pragma unroll
    for (int i = 0; i < 4; ++i) af[i] = *(const bf16x8*)&sA0[(wr * 8 + 4 + i) * 512 + fo];
    if (T + 1 < nt) STG_B(nb, 1, T + 1);
    __builtin_amdgcn_s_barrier();
    asm volatile("s_waitcnt lgkmcnt(0)" ::: "memory");
    __builtin_amdgcn_sched_barrier(0);
    __builtin_amdgcn_s_setprio(1);
#pragma unroll
    for (int mi = 0; mi < 4; ++mi)
#pragma unroll
      for (int ni = 0; ni < 4; ++ni)
        acc[4 + mi][ni] = __builtin_amdgcn_mfma_f32_16x16x32_bf16(af[mi], bfr[ni], acc[4 + mi][ni], 0, 0, 0);
    __builtin_amdgcn_s_setprio(0);
    __builtin_amdgcn_s_barrier();

    // ---- ph3: kh1, m-half0 ----
#pragma unroll
    for (int i = 0; i < 4; ++i) af[i]  = *(const bf16x8*)&sA1[(wr * 8 + i) * 512 + fo];
#pragma unroll
    for (int i = 0; i < 4; ++i) bfr[i] = *(const bf16x8*)&sB1[(wc * 4 + i) * 512 + fo];
    if (T + 2 < nt) STG_A(bb, 0, T + 2);
    __builtin_amdgcn_s_barrier();
    asm volatile("s_waitcnt lgkmcnt(0)" ::: "memory");
    __builtin_amdgcn_sched_barrier(0);
    __builtin_amdgcn_s_setprio(1);
#pragma unroll
    for (int mi = 0; mi < 4; ++mi)
#pragma unroll
      for (int ni = 0; ni < 4; ++ni)
        acc[mi][ni] = __builtin_amdgcn_mfma_f32_16x16x32_bf16(af[mi], bfr[ni], acc[mi][ni], 0, 0, 0);
    __builtin_amdgcn_s_setprio(0);
    __builtin_amdgcn_s_barrier();

    // ---- ph4: kh1, m-half1 ----
#pragma unroll
    for (int i = 0; i < 4; ++i) af[i] = *(const bf16x8*)&sA1[(wr * 8 + 4 + i) * 512 + fo];
    if (T + 2 < nt) STG_B(bb, 0, T + 2);
    __builtin_amdgcn_s_barrier();
    asm volatile("s_waitcnt lgkmcnt(0)" ::: "memory");
    __builtin_amdgcn_sched_barrier(0);
    __builtin_amdgcn_s_setprio(1);
#pragma unroll
    for (int mi = 0; mi < 4; ++mi)
#pragma unroll
      for (int ni = 0; ni < 4; ++ni)
        acc[4 + mi][ni] = __builtin_amdgcn_mfma_f32_16x16x32_bf16(af[mi], bfr[ni], acc[4 + mi][ni], 0, 0, 0);
    __builtin_amdgcn_s_setprio(0);

    // ---- tile gate: b1(T+1)+older must land; a0/b0(T+2) may fly ----
    if (T + 2 < nt) asm volatile("s_waitcnt vmcnt(4)" ::: "memory");
    else            asm volatile("s_waitcnt vmcnt(0)" ::: "memory");
    __builtin_amdgcn_s_barrier();
  }
#undef STG_A
#undef STG_B

  // ---- epilogue: LDS-transpose to row-major vectorized stores ----
  float* cs = (float*)smem + wave * 1088;    // wave-private 16 x 68 f32
  float bv[4];
#pragma unroll
  for (int ni = 0; ni < 4; ++ni) bv[ni] = bias[ncol0 + wc * 64 + ni * 16 + lr];
  const int er = lane >> 2;                  // 0..15: row within 16-row group
  const int ec = (lane & 3) * 16;            // col block within 64

#pragma unroll
  for (int mi = 0; mi < 8; ++mi) {
#pragma unroll
    for (int ni = 0; ni < 4; ++ni)
#pragma unroll
      for (int r = 0; r < 4; ++r)
        cs[(g * 4 + r) * 68 + ni * 16 + lr] = acc[mi][ni][r] + bv[ni];
    const long grow = m0 + wr * 128 + mi * 16 + er;
    const long gcol = ncol0 + wc * 64 + ec;
    float vals[16];
#pragma unroll
    for (int jb = 0; jb < 4; ++jb) {
      float4 v = *(const float4*)&cs[er * 68 + ec + jb * 4];
      vals[jb * 4 + 0] = v.x; vals[jb * 4 + 1] = v.y;
      vals[jb * 4 + 2] = v.z; vals[jb * 4 + 3] = v.w;
    }
    if (RESID) {
      const float* rp = resid + grow * (long)nsplit + gcol;
#pragma unroll
      for (int jb = 0; jb < 4; ++jb) {
        float4 v = *(const float4*)&rp[jb * 4];
        vals[jb * 4 + 0] += v.x; vals[jb * 4 + 1] += v.y;
        vals[jb * 4 + 2] += v.z; vals[jb * 4 + 3] += v.w;
      }
    }
    if (OUT_BF16) {
      union { short sh[16]; int4 q[2]; } o;
#pragma unroll
      for (int j = 0; j < 16; ++j) o.sh[j] = f2bf(vals[j]);
      short* op = (short*)outp + grow * (long)nsplit + gcol;
      *(int4*)op = o.q[0];
      *(int4*)(op + 8) = o.q[1];
    } else {
      float* op = (float*)outp + grow * (long)nsplit + gcol;
#pragma unroll
      for (int jb = 0; jb < 4; ++jb)
        *(float4*)&op[jb * 4] = make_float4(vals[jb * 4 + 0], vals[jb * 4 + 1],
                                            vals[jb * 4 + 2], vals[jb * 4 + 3]);
    }
  }
}

// ---- fused feature attention + residual + LN2, one block per (b,e) ----
__global__ __launch_bounds__(256) void attn_kernel(
    const short* __restrict__ q, const short* __restrict__ k,
    const short* __restrict__ v, const float* __restrict__ x,
    const float* __restrict__ wn_g, const float* __restrict__ wn_b,
    const float* __restrict__ ln2_g, const float* __restrict__ ln2_b,
    float* __restrict__ x1, short* __restrict__ h2) {
  __shared__ float att_s[64][68];
  const int t = threadIdx.x;
  const int wave = t >> 6, lane = t & 63;
  const int lr = lane & 15, g = lane >> 4;
  const long base = (long)blockIdx.x * 64;
  const long qoff = base * D_DIM;

  const f32x4 vzero = {0.f, 0.f, 0.f, 0.f};
  f32x4 acc[4];
#pragma unroll
  for (int nt = 0; nt < 4; ++nt) acc[nt] = vzero;

  for (int ks = 0; ks < 16; ++ks) {
    const int kc = ks * 32 + g * 8;
    bf16x8 afr = *(const bf16x8*)&q[qoff + (long)(wave * 16 + lr) * D_DIM + kc];
#pragma unroll
    for (int nt = 0; nt < 4; ++nt) {
      bf16x8 bfr = *(const bf16x8*)&k[qoff + (long)(nt * 16 + lr) * D_DIM + kc];
      acc[nt] = __builtin_amdgcn_mfma_f32_16x16x32_bf16(afr, bfr, acc[nt], 0, 0, 0);
    }
  }

  const float scale = 0.044194173824159216f;  // 1/sqrt(512)
#pragma unroll
  for (int r = 0; r < 4; ++r) {
    float s = 0.f, ss = 0.f;
#pragma unroll
    for (int nt = 0; nt < 4; ++nt) { float e = acc[nt][r]; s += e; ss += e * e; }
#pragma unroll
    for (int m = 1; m < 16; m <<= 1) { s += __shfl_xor(s, m); ss += __shfl_xor(ss, m); }
    float mean = s * (1.f / 64);
    float var  = ss * (1.f / 64) - mean * mean;
    float rstd = rsqrtf(var + 1e-5f);
    float e[4]; float mx = -1e30f;
#pragma unroll
    for (int nt = 0; nt < 4; ++nt) {
      int col = nt * 16 + lr;
      e[nt] = ((acc[nt][r] - mean) * rstd * wn_g[col] + wn_b[col]) * scale;
      mx = fmaxf(mx, e[nt]);
    }
#pragma unroll
    for (int m = 1; m < 16; m <<= 1) mx = fmaxf(mx, __shfl_xor(mx, m));
    float se = 0.f;
#pragma unroll
    for (int nt = 0; nt < 4; ++nt) { e[nt] = expf(e[nt] - mx); se += e[nt]; }
#pragma unroll
    for (int m = 1; m < 16; m <<= 1) se += __shfl_xor(se, m);
    float inv = 1.f / se;
#pragma unroll
    for (int nt = 0; nt < 4; ++nt)
      att_s[wave * 16 + 4 * g + r][nt * 16 + lr] = e[nt] * inv;
  }
  __syncthreads();

  const int d0 = lane * 8;
  float accp[16][8];
#pragma unroll
  for (int qi = 0; qi < 16; ++qi)
#pragma unroll
    for (int j = 0; j < 8; ++j) accp[qi][j] = 0.f;

  for (int kk0 = 0; kk0 < 64; kk0 += 4) {
    float vf[4][8];
#pragma unroll
    for (int kc = 0; kc < 4; ++kc) {
      bf16x8 vv = *(const bf16x8*)&v[qoff + (long)(kk0 + kc) * D_DIM + d0];
#pragma unroll
      for (int j = 0; j < 8; ++j) vf[kc][j] = bf2f(vv[j]);
    }
#pragma unroll
    for (int qi = 0; qi < 16; ++qi) {
      float4 a4 = *(const float4*)&att_s[wave * 16 + qi][kk0];
#pragma unroll
      for (int j = 0; j < 8; ++j) {
        accp[qi][j] += a4.x * vf[0][j];
        accp[qi][j] += a4.y * vf[1][j];
        accp[qi][j] += a4.z * vf[2][j];
        accp[qi][j] += a4.w * vf[3][j];
      }
    }
  }

  float g2v[8], b2v[8];
#pragma unroll
  for (int j = 0; j < 8; ++j) { g2v[j] = ln2_g[d0 + j]; b2v[j] = ln2_b[d0 + j]; }

#pragma unroll
  for (int qi = 0; qi < 16; ++qi) {
    const long row = base + wave * 16 + qi;
    const float* xr = x + row * D_DIM + d0;
    float4 x0 = *(const float4*)xr;
    float4 xb = *(const float4*)(xr + 4);
    accp[qi][0] += x0.x; accp[qi][1] += x0.y;
    accp[qi][2] += x0.z; accp[qi][3] += x0.w;
    accp[qi][4] += xb.x; accp[qi][5] += xb.y;
    accp[qi][6] += xb.z; accp[qi][7] += xb.w;
    float* po = x1 + row * D_DIM + d0;
    *(float4*)po       = make_float4(accp[qi][0], accp[qi][1], accp[qi][2], accp[qi][3]);
    *(float4*)(po + 4) = make_float4(accp[qi][4], accp[qi][5], accp[qi][6], accp[qi][7]);
    float s = 0.f, ss = 0.f;
#pragma unroll
    for (int j = 0; j < 8; ++j) { s += accp[qi][j]; ss += accp[qi][j] * accp[qi][j]; }
#pragma unroll
    for (int m = 1; m < 64; m <<= 1) { s += __shfl_xor(s, m); ss += __shfl_xor(ss, m); }
    float mean = s * (1.f / D_DIM);
    float var  = ss * (1.f / D_DIM) - mean * mean;
    float rstd = rsqrtf(var + 1e-5f);
    union { short sh[8]; int4 v; } o;
#pragma unroll
    for (int j = 0; j < 8; ++j)
      o.sh[j] = f2bf((accp[qi][j] - mean) * rstd * g2v[j] + b2v[j]);
    *(int4*)&h2[row * D_DIM + d0] = o.v;
  }
}

extern "C" void kernel_launch(void* const* d_in, const int* in_sizes, int n_in,
                              void* d_out, int out_size, void* d_ws, size_t ws_size,
                              hipStream_t stream) {
  (void)in_sizes; (void)n_in; (void)out_size; (void)ws_size;
  const float* x     = (const float*)d_in[0];
  const float* ln1_g = (const float*)d_in[1];
  const float* ln1_b = (const float*)d_in[2];
  const float* Wq    = (const float*)d_in[3];
  const float* bq    = (const float*)d_in[4];
  const float* Wk    = (const float*)d_in[5];
  const float* bk    = (const float*)d_in[6];
  const float* Wv    = (const float*)d_in[7];
  const float* bv    = (const float*)d_in[8];
  const float* wn_g  = (const float*)d_in[9];
  const float* wn_b  = (const float*)d_in[10];
  const float* ln2_g = (const float*)d_in[11];
  const float* ln2_b = (const float*)d_in[12];
  const float* W1    = (const float*)d_in[13];
  const float* b1    = (const float*)d_in[14];
  const float* W2    = (const float*)d_in[15];
  const float* b2    = (const float*)d_in[16];
  float* out = (float*)d_out;

  char* ws = (char*)d_ws;
  short* h   = (short*)(ws);                                  // 32 MB (h, then h2)
  short* qb  = (short*)(ws + (size_t)32  * 1024 * 1024);      // 32 MB
  short* kb  = (short*)(ws + (size_t)64  * 1024 * 1024);      // 32 MB
  short* vb  = (short*)(ws + (size_t)96  * 1024 * 1024);      // 32 MB
  short* ff1 = (short*)(ws + (size_t)32  * 1024 * 1024);      // 128 MB, aliases dead q/k/v
  short* Wqt = (short*)(ws + (size_t)160 * 1024 * 1024);      // [1536][512] contiguous qkv
  short* Wkt = Wqt + 512 * 512;
  short* Wvt = Wkt + 512 * 512;
  short* W1t = Wvt + 512 * 512;                               // [2048][512]
  short* W2t = W1t + 512 * 2048;                              // [512][2048]

  const size_t lds_bytes = 131072;
  (void)hipFuncSetAttribute((const void*)gemm256<1, 0>,
      hipFuncAttributeMaxDynamicSharedMemorySize, (int)lds_bytes);
  (void)hipFuncSetAttribute((const void*)gemm256<0, 1>,
      hipFuncAttributeMaxDynamicSharedMemorySize, (int)lds_bytes);

  wconvT<<<dim3(512 / 32, 512 / 32),  256, 0, stream>>>(Wq, Wqt, 512, 512);
  wconvT<<<dim3(512 / 32, 512 / 32),  256, 0, stream>>>(Wk, Wkt, 512, 512);
  wconvT<<<dim3(512 / 32, 512 / 32),  256, 0, stream>>>(Wv, Wvt, 512, 512);
  wconvT<<<dim3(2048 / 32, 512 / 32), 256, 0, stream>>>(W1, W1t, 512, 2048);
  wconvT<<<dim3(512 / 32, 2048 / 32), 256, 0, stream>>>(W2, W2t, 2048, 512);

  ln_kernel<<<NROWS / 4, 256, 0, stream>>>(x, ln1_g, ln1_b, h);

  dim3 gqkv(1536 / 256, NROWS / 256);   // (6, 128) = 768 blocks
  gemm256<1, 0><<<gqkv, 512, lds_bytes, stream>>>(h, Wqt, bq, bk, bv,
                                                  qb, kb, vb, nullptr, 512, 512);

  attn_kernel<<<NBE, 256, 0, stream>>>(qb, kb, vb, x, wn_g, wn_b,
                                       ln2_g, ln2_b, out, h);

  dim3 gff1(2048 / 256, NROWS / 256);   // (8, 128) = 1024 blocks
  gemm256<1, 0><<<gff1, 512, lds_bytes, stream>>>(h, W1t, b1, b1, b1,
                                                  ff1, ff1, ff1, nullptr, 512, 2048);

  dim3 gff2(512 / 256, NROWS / 256);    // (2, 128) = 256 blocks
  gemm256<0, 1><<<gff2, 512, lds_bytes, stream>>>(ff1, W2t, b2, b2, b2,
                                                  out, out, out, out, 2048, 512);
}